// Round 7
// baseline (466.476 us; speedup 1.0000x reference)
//
#include <hip/hip_runtime.h>
#include <stdint.h>

// PrecondTiming round 14. 3-pass + reduce. THE change: static 2-tile
// pairing with register prefetch -- r13's MLP gain without its locality
// loss.
//   r13 evidence: ticketed persistent blocks raised K2 BW 1.87->2.24TB/s
//   (MLP theory CONFIRMED) but FETCH 122->224MB (desynced blocks kept ~5
//   pin2node slices live per XCD; items1 L3-retention lost) -> net
//   regression. Fix: each block statically owns TWO consecutive tiles of
//   the SAME residue (K1: r+8*2sp, r+8*(2sp+1); K2: same r2, consecutive
//   s) -> concurrent blocks contiguous in blockIdx = r12's exact
//   traversal (FETCH should return to ~122MB), and tile B's loads (+
//   dependent pin2node gathers in K2) issue after tile A's pass D,
//   overlapping pass E + pass A + scan. LDS-only BAR() keeps them in
//   flight across barriers.
// Dead theories (measured): bulk global atomics (r8 826us), unbinned
// gather (r9 370us), barrier count (r10), counter contention (r11),
// register spill (r12), dynamic tickets (r13 locality loss).

#define TILE 4096
#define THREADS 512
#define IPT  8                   // items per thread (TILE / THREADS)
#define NB1  40
#define SHIFT1 19                // pin >> 19 : 40 bins cover 20,971,520 pins
#define CAP1R 55296              // per (bin,residue); expected 52,429 (+12.7s)
#define TPB1R 14                 // ceil(CAP1R / TILE)
#define NB2  64
#define SHIFT2 14                // node >> 14 : 64 bins cover 2^20 nodes
#define CAP2R 34816              // per (bin,residue); expected 32,768 (+11.4s)
#define ACC_NODES 16384          // nodes per node-bin
#define PARTS 8                  // accumulate blocks per node-bin = residues
#define CLINE_INTS 16            // one counter per 64B cache line
#define CTRL_BYTES 65536         // ctrl1 @0 (40*8 lines), ctrl2 @32768 (64*8)
#define SPR2 (5 * 8 * TPB1R)     // 560 K2 tiles per residue (5 grp x 8 wr x 14)

typedef unsigned long long item_t;   // low32 = key (pin or node), high32 = w
typedef int   int4_ev   __attribute__((ext_vector_type(4)));
typedef float float4_ev __attribute__((ext_vector_type(4)));
typedef unsigned long long ull2_ev __attribute__((ext_vector_type(2)));

// LDS-only barrier: waits DS ops, NOT vmem (keeps prefetch loads +
// nontemporal stores in flight across phases). All phase deps are LDS.
#define BAR() do { __builtin_amdgcn_sched_barrier(0); \
    asm volatile("s_waitcnt lgkmcnt(0)" ::: "memory"); \
    __builtin_amdgcn_s_barrier(); \
    __builtin_amdgcn_sched_barrier(0); } while (0)

__device__ __forceinline__ item_t pack_item(uint32_t key, float w) {
    return (item_t)key | ((item_t)__float_as_uint(w) << 32);
}

// ---- multisplit phases (512 thr, <=256 bins, bin = key >> shift) ----
__device__ __forceinline__ void ms_passA(item_t (&e)[IPT], int vcnt, int shift,
                                         int* hist, uint32_t (&rankp)[IPT / 2]) {
#pragma unroll
    for (int k = 0; k < IPT; ++k) {
        int b = (int)((uint32_t)e[k] >> shift);
        uint32_t rr = (k < vcnt) ? (uint32_t)atomicAdd(&hist[b], 1) : 0u;
        if ((k & 1) == 0) rankp[k >> 1] = rr;
        else              rankp[k >> 1] |= (rr << 16);
    }
}

// between B2 and B4; contains one BAR; re-zeroes hist for the next tile
__device__ __forceinline__ void ms_scan(int t, int* hist, unsigned long long* combo,
                                        int* wsum, int* gcur, int gcur_stride) {
    int val = (t < 256) ? hist[t] : 0;
    int inc = val;
#pragma unroll
    for (int d = 1; d < 64; d <<= 1) {
        int n = __shfl_up(inc, d, 64);
        if ((t & 63) >= d) inc += n;
    }
    if (t < 256 && (t & 63) == 63) wsum[t >> 6] = inc;
    BAR();                                            // B3
    if (t < 256) {
        hist[t] = 0;
        int w = t >> 6, prefix = 0;
        if (w > 0) prefix += wsum[0];
        if (w > 1) prefix += wsum[1];
        if (w > 2) prefix += wsum[2];
        int bx = prefix + inc - val;                  // exclusive base
        int gb = (val > 0) ? atomicAdd(&gcur[t * gcur_stride], val) : 0;
        combo[t] = ((unsigned long long)(uint32_t)gb << 32) | (uint32_t)bx;
    }
}

__device__ __forceinline__ void ms_passD(item_t (&e)[IPT], int vcnt, int shift,
                                         uint32_t (&rankp)[IPT / 2],
                                         unsigned long long* combo, item_t* stage) {
#pragma unroll
    for (int k = 0; k < IPT; ++k) {
        if (k < vcnt) {
            int b = (int)((uint32_t)e[k] >> shift);
            int rr = (int)((rankp[k >> 1] >> ((k & 1) * 16)) & 0xffffu);
            stage[(int)((uint32_t)combo[b]) + rr] = e[k];
        }
    }
}

__device__ __forceinline__ void ms_passE(int t, item_t* stage, int tile_cnt, int shift,
                                         unsigned long long* combo,
                                         item_t* gout, size_t bin_stride, size_t cap) {
    for (int j = t; j < tile_cnt; j += THREADS) {
        item_t ev = stage[j];
        int b = (int)((uint32_t)(ev & 0xffffffffull) >> shift);
        unsigned long long c = combo[b];
        long long dst = (long long)(int)(c >> 32) + (j - (int)(uint32_t)c);
        if (dst >= 0 && dst < (long long)cap)
            __builtin_nontemporal_store(ev, &gout[(size_t)b * bin_stride + (size_t)dst]);
    }
}

// ---- K1 tile load: pins + weights -> packed e[] ----
__device__ __forceinline__ void k1_load(
    const int* __restrict__ flat_pins, const float* __restrict__ weights,
    int total, int tb, int t, item_t (&e)[IPT], int& vcnt, int& tcnt)
{
    const int base = tb + t * IPT;
    int tc = total - tb; tc = tc < 0 ? 0 : (tc > TILE ? TILE : tc);
    tcnt = tc;
    if (base + IPT <= total) {
        vcnt = IPT;
        int4_ev p0 = __builtin_nontemporal_load((const int4_ev*)(flat_pins + base));
        int4_ev p1 = __builtin_nontemporal_load((const int4_ev*)(flat_pins + base) + 1);
        float4_ev w = __builtin_nontemporal_load((const float4_ev*)(weights + (base >> 1)));
#pragma unroll
        for (int k = 0; k < IPT; ++k)
            e[k] = pack_item((uint32_t)((k < 4) ? p0[k & 3] : p1[k & 3]), w[(k >> 1) & 3]);
    } else {
        int rem = total - base;
        vcnt = rem < 0 ? 0 : (rem > IPT ? IPT : rem);
#pragma unroll
        for (int k = 0; k < IPT; ++k) {
            int i = base + k;
            e[k] = (i < total) ? pack_item((uint32_t)flat_pins[i], weights[i >> 1]) : 0ull;
        }
    }
}

// ---- K1: 2 consecutive same-residue tiles per block, prefetch second ----
__global__ __launch_bounds__(THREADS, 8) void k1_partition_pins(
    const int* __restrict__ flat_pins, const float* __restrict__ weights,
    int* __restrict__ ctrl1, item_t* __restrict__ items1, int total)
{
    __shared__ int hist[256];
    __shared__ unsigned long long combo[256];
    __shared__ int wsum[4];
    __shared__ item_t stage[TILE];

    const int t = threadIdx.x;
    const int r = blockIdx.x & 7;               // residue: fixed per block
    const int sp = blockIdx.x >> 3;             // pair index within residue
    int* mycur = ctrl1 + r * CLINE_INTS;
    item_t* mout = items1 + (size_t)r * CAP1R;

    if (t < 256) hist[t] = 0;

    item_t e[IPT];
    int vcnt, tcnt;
    const int j0 = r + 8 * (2 * sp);            // global tile index, tile A
    k1_load(flat_pins, weights, total, j0 * TILE, t, e, vcnt, tcnt);
    __syncthreads();

#pragma unroll 1
    for (int it = 0; it < 2; ++it) {
        uint32_t rankp[IPT / 2];
        ms_passA(e, vcnt, SHIFT1, hist, rankp);
        BAR();                                        // B2
        ms_scan(t, hist, combo, wsum, mycur, 8 * CLINE_INTS);
        BAR();                                        // B4
        ms_passD(e, vcnt, SHIFT1, rankp, combo, stage);
        BAR();                                        // B5
        const int tcnt_cur = tcnt;
        if (it == 0) {                                // prefetch tile B (j0+8)
            k1_load(flat_pins, weights, total, (j0 + 8) * TILE, t, e, vcnt, tcnt);
        }
        ms_passE(t, stage, tcnt_cur, SHIFT1, combo, mout,
                 (size_t)8 * CAP1R, (size_t)CAP1R);
        BAR();                                        // Bend
    }
}

// ---- K2: 2 consecutive same-residue s-slots per block; gather via
// ---- L2-resident slice; prefetch+gather second slot during first ----
__global__ __launch_bounds__(THREADS, 8) void k2_gather_partition(
    const item_t* __restrict__ items1, const int* __restrict__ ctrl1,
    const int* __restrict__ pin2node,
    int* __restrict__ ctrl2, item_t* __restrict__ items2)
{
    __shared__ int hist[256];
    __shared__ unsigned long long combo[256];
    __shared__ int wsum[4];
    __shared__ item_t stage[TILE];
    __shared__ int sh_cnt[NB1];          // this residue's 5 bins x 8 writers

    const int t = threadIdx.x;
    const int r2 = blockIdx.x & 7;       // XCD residue (r6-verified affinity)
    const int sp = blockIdx.x >> 3;      // pair index: s = 2sp, 2sp+1
    int* mycur = ctrl2 + r2 * CLINE_INTS;
    item_t* mout = items2 + (size_t)r2 * CAP2R;

    if (t < 256) hist[t] = 0;
    if (t < NB1) {
        int bin = r2 + 8 * (t >> 3);
        sh_cnt[t] = min(ctrl1[(bin * 8 + (t & 7)) * CLINE_INTS], (int)CAP1R);
    }
    __syncthreads();

#define GMERGE(slot, ev_) { item_t ev = (ev_); \
        int nd = pin2node[(uint32_t)ev]; \
        e[slot] = (ev & 0xffffffff00000000ull) | (uint32_t)nd; }

#define K2_LOAD(sidx) { \
        int s_ = (sidx); \
        int g_ = s_ / (8 * TPB1R), rem_ = s_ % (8 * TPB1R); \
        int rw_ = rem_ / TPB1R, tile_ = rem_ % TPB1R; \
        int bin_ = r2 + 8 * g_; \
        int cnt_ = sh_cnt[(g_ << 3) | rw_]; \
        int tb_ = tile_ * TILE; \
        int tc_ = cnt_ - tb_; tc_ = tc_ < 0 ? 0 : (tc_ > TILE ? TILE : tc_); \
        tcnt = tc_; \
        const item_t* src_ = items1 + ((size_t)bin_ * 8 + (size_t)rw_) * CAP1R; \
        int base_ = tb_ + t * IPT; \
        if (base_ + IPT <= cnt_) { \
            vcnt = IPT; \
            ull2_ev x0 = __builtin_nontemporal_load((const ull2_ev*)(src_ + base_)); \
            ull2_ev x1 = __builtin_nontemporal_load((const ull2_ev*)(src_ + base_) + 1); \
            ull2_ev x2 = __builtin_nontemporal_load((const ull2_ev*)(src_ + base_) + 2); \
            ull2_ev x3 = __builtin_nontemporal_load((const ull2_ev*)(src_ + base_) + 3); \
            GMERGE(0, x0[0]) GMERGE(1, x0[1]) GMERGE(2, x1[0]) GMERGE(3, x1[1]) \
            GMERGE(4, x2[0]) GMERGE(5, x2[1]) GMERGE(6, x3[0]) GMERGE(7, x3[1]) \
        } else { \
            int rem2_ = cnt_ - base_; \
            vcnt = rem2_ < 0 ? 0 : (rem2_ > IPT ? IPT : rem2_); \
            _Pragma("unroll") \
            for (int k = 0; k < IPT; ++k) { \
                int i_ = base_ + k; \
                if (i_ < cnt_) { GMERGE(k, src_[i_]) } else e[k] = 0ull; \
            } \
        } }

    item_t e[IPT];
    int vcnt, tcnt;
    K2_LOAD(2 * sp);

#pragma unroll 1
    for (int it = 0; it < 2; ++it) {
        uint32_t rankp[IPT / 2];
        ms_passA(e, vcnt, SHIFT2, hist, rankp);
        BAR();                                        // B2
        ms_scan(t, hist, combo, wsum, mycur, 8 * CLINE_INTS);
        BAR();                                        // B4
        ms_passD(e, vcnt, SHIFT2, rankp, combo, stage);
        BAR();                                        // B5
        const int tcnt_cur = tcnt;
        if (it == 0) {                                // prefetch + gather s+1
            K2_LOAD(2 * sp + 1);
        }
        ms_passE(t, stage, tcnt_cur, SHIFT2, combo, mout,
                 (size_t)8 * CAP2R, (size_t)CAP2R);
        BAR();                                        // Bend
    }
#undef K2_LOAD
#undef GMERGE
}

// ---- K3: LDS accumulate per (node-bin, residue); 4-stream dense loads,
// ---- 1-deep A/B named-register prefetch (rule-#20-safe) ----
__global__ __launch_bounds__(1024, 8) void k3_accumulate_part(
    const item_t* __restrict__ items2, const int* __restrict__ ctrl2,
    float* __restrict__ partials)
{
    __shared__ float acc[ACC_NODES];
    const int b = blockIdx.x >> 3;
    const int p = blockIdx.x & (PARTS - 1);
    const int t = threadIdx.x;
    for (int i = t; i < ACC_NODES; i += 1024) acc[i] = 0.f;
    __syncthreads();

    const int cnt = min(ctrl2[(b * 8 + p) * CLINE_INTS], (int)CAP2R);
    const item_t* src = items2 + ((size_t)b * 8 + (size_t)p) * CAP2R;
    const ull2_ev* src2 = (const ull2_ev*)src;
    const int npair = cnt >> 1;
    const int quarter = npair >> 2;

#define K3_LOAD(A0, A1, A2, A3, g) { \
    A0 = __builtin_nontemporal_load(src2 + (g)); \
    A1 = __builtin_nontemporal_load(src2 + quarter + (g)); \
    A2 = __builtin_nontemporal_load(src2 + 2 * quarter + (g)); \
    A3 = __builtin_nontemporal_load(src2 + 3 * quarter + (g)); }
#define K3_ACC1(ev) atomicAdd(&acc[(uint32_t)(ev) & (ACC_NODES - 1)], \
                              __uint_as_float((uint32_t)((ev) >> 32)))
#define K3_PROC(A0, A1, A2, A3) { \
    K3_ACC1(A0[0]); K3_ACC1(A0[1]); K3_ACC1(A1[0]); K3_ACC1(A1[1]); \
    K3_ACC1(A2[0]); K3_ACC1(A2[1]); K3_ACC1(A3[0]); K3_ACC1(A3[1]); }

    ull2_ev a0, a1, a2, a3, b0, b1, b2, b3;
    int g = t;
    bool vA = g < quarter;
    if (vA) K3_LOAD(a0, a1, a2, a3, g)
    int gB = g + 1024;
    while (vA) {
        bool vB = gB < quarter;
        if (vB) K3_LOAD(b0, b1, b2, b3, gB)
        K3_PROC(a0, a1, a2, a3)
        g = gB + 1024;
        vA = g < quarter;
        if (vA) K3_LOAD(a0, a1, a2, a3, g)
        if (vB) K3_PROC(b0, b1, b2, b3)
        gB = g + 1024;
    }
    for (int i = (quarter << 3) + t; i < cnt; i += 1024) {  // tail
        item_t ev = src[i];
        K3_ACC1(ev);
    }
#undef K3_LOAD
#undef K3_ACC1
#undef K3_PROC
    __syncthreads();
    float* __restrict__ dst = partials + (size_t)blockIdx.x * ACC_NODES;
    for (int i = t; i < ACC_NODES; i += 1024) dst[i] = acc[i];
}

// ---- K4: out[n] = beta * sum over PARTS partials (32MB streamed) ----
__global__ __launch_bounds__(256) void k4_reduce(
    const float* __restrict__ partials, const float* __restrict__ beta,
    float* __restrict__ out, int num_nodes)
{
    const float bt = beta[0];
    const int n = (blockIdx.x * 256 + threadIdx.x) << 2;
    if (n + 3 < num_nodes) {
        const int b   = n >> SHIFT2;
        const int off = n & (ACC_NODES - 1);
        const float* base = partials + ((size_t)b * PARTS) * ACC_NODES + off;
        float4_ev s = {0.f, 0.f, 0.f, 0.f};
#pragma unroll
        for (int p = 0; p < PARTS; ++p)
            s += *(const float4_ev*)(base + (size_t)p * ACC_NODES);
        *(float4_ev*)(out + n) = s * bt;
    } else {
        for (int k = 0; k < 4; ++k) {
            int nn = n + k;
            if (nn < num_nodes) {
                const int b   = nn >> SHIFT2;
                const int off = nn & (ACC_NODES - 1);
                float s = 0.f;
#pragma unroll
                for (int p = 0; p < PARTS; ++p)
                    s += partials[((size_t)b * PARTS + p) * ACC_NODES + off];
                out[nn] = s * bt;
            }
        }
    }
}

// ---- fallback (round-1, known-good ~830us): device-scope atomics ----
__global__ __launch_bounds__(256) void scatter_device(
    const float* __restrict__ beta, const float* __restrict__ tnet_weights,
    const long long* __restrict__ pin_pairs, const int* __restrict__ pin2node_map,
    float* __restrict__ out, int num_tnets)
{
    int t = blockIdx.x * blockDim.x + threadIdx.x;
    if (t >= num_tnets) return;
    long long pp = pin_pairs[t];
    float w = tnet_weights[t] * beta[0];
    atomicAdd(&out[pin2node_map[(int)(pp & 0xffffffffLL)]], w);
    atomicAdd(&out[pin2node_map[(int)(pp >> 32)]], w);
}

extern "C" void kernel_launch(void* const* d_in, const int* in_sizes, int n_in,
                              void* d_out, int out_size, void* d_ws, size_t ws_size,
                              hipStream_t stream) {
    const float* beta         = (const float*)d_in[0];
    const float* weights      = (const float*)d_in[1];
    const int*   flat_pins    = (const int*)d_in[2];
    const int*   pin2node     = (const int*)d_in[3];
    float* out = (float*)d_out;

    const int num_tnets = in_sizes[1];
    const int total     = in_sizes[2];       // 2 * num_tnets flat pin slots
    const int num_nodes = out_size;

    const size_t items1Bytes = (size_t)NB1 * 8 * CAP1R * sizeof(item_t);  // 141.6 MB
    const size_t items2Bytes = (size_t)NB2 * 8 * CAP2R * sizeof(item_t);  // 142.6 MB
    const size_t partBytes   = (size_t)NB2 * PARTS * ACC_NODES * sizeof(float); // 32 MB

    int* ctrl1 = (int*)d_ws;                           // 40*8 padded counters
    int* ctrl2 = (int*)((char*)d_ws + 32768);          // 64*8 padded counters

    if (ws_size >= CTRL_BYTES + items1Bytes + items2Bytes + partBytes) {
        item_t* items1 = (item_t*)((char*)d_ws + CTRL_BYTES);
        item_t* items2 = (item_t*)((char*)d_ws + CTRL_BYTES + items1Bytes);
        float*  partials = (float*)((char*)d_ws + CTRL_BYTES + items1Bytes + items2Bytes);
        (void)hipMemsetAsync(d_ws, 0, CTRL_BYTES, stream);

        const int gridTiles = (total + TILE - 1) / TILE;
        const int tilesPerRes = (gridTiles + 7) / 8;          // max tiles/residue
        const int k1Blocks = 8 * ((tilesPerRes + 1) / 2);     // 2 tiles/block
        k1_partition_pins<<<k1Blocks, THREADS, 0, stream>>>(
            flat_pins, weights, ctrl1, items1, total);
        k2_gather_partition<<<8 * (SPR2 / 2), THREADS, 0, stream>>>(
            items1, ctrl1, pin2node, ctrl2, items2);
        k3_accumulate_part<<<NB2 * PARTS, 1024, 0, stream>>>(
            items2, ctrl2, partials);
        const int i4slots = (num_nodes + 3) / 4;
        k4_reduce<<<(i4slots + 255) / 256, 256, 0, stream>>>(
            partials, beta, out, num_nodes);
    } else {
        (void)hipMemsetAsync(d_out, 0, (size_t)out_size * sizeof(float), stream);
        scatter_device<<<(num_tnets + 255) / 256, 256, 0, stream>>>(
            beta, weights, (const long long*)flat_pins, pin2node, out, num_tnets);
    }
}